// Round 1
// baseline (152.392 us; speedup 1.0000x reference)
//
#include <hip/hip_runtime.h>
#include <hip/hip_bf16.h>

#define N_NODES 40000
#define N_EDGES 640000
#define N_FEAT 64
#define HIDDEN 128
#define N_GRAPHS 256
#define CAP 64  // max in-degree (deg ~ Poisson(16); P(>64) ~ 1e-19)

typedef unsigned short ushort_t;
typedef unsigned int uint_t;
typedef __bf16 bf16x8 __attribute__((ext_vector_type(8)));
typedef float f32x4 __attribute__((ext_vector_type(4)));

__device__ inline float b2f_lo(uint_t v) {
  return __builtin_bit_cast(float, v << 16);
}
__device__ inline float b2f_hi(uint_t v) {
  return __builtin_bit_cast(float, v & 0xffff0000u);
}
__device__ inline ushort_t f2b(float f) {
  return __builtin_bit_cast(ushort_t, __float2bfloat16(f));
}
__device__ inline uint_t pack2(float lo, float hi) {
  return (uint_t)f2b(lo) | ((uint_t)f2b(hi) << 16);
}

// ---------------------------------------------------------------------------
// Prep: blocks [0,2500): bucket fill (int atomic bump).
//       blocks [2500,2852): weight transposes f32[K][128] -> bf16 [128][K].
//       blocks [2852,4102): x f32 -> bf16, VECTORIZED 8 floats/thread.
//       blocks [4102,4230): zero g.
// ---------------------------------------------------------------------------
__global__ __launch_bounds__(256) void prep_kernel(
    const int* __restrict__ src, const int* __restrict__ dst,
    int* __restrict__ cnt, int* __restrict__ bucket,
    const float* __restrict__ W1a, const float* __restrict__ W1b,
    const float* __restrict__ W2a, const float* __restrict__ W2b,
    const float* __restrict__ W3a, const float* __restrict__ W3b,
    const float* __restrict__ x, ushort_t* __restrict__ T1a,
    ushort_t* __restrict__ T1b, ushort_t* __restrict__ T2a,
    ushort_t* __restrict__ T2b, ushort_t* __restrict__ T3a,
    ushort_t* __restrict__ T3b, ushort_t* __restrict__ xb,
    float* __restrict__ g) {
  const int blk = blockIdx.x;
  if (blk < 2500) {
    int e = blk * 256 + threadIdx.x;  // exactly N_EDGES
    int d = dst[e];
    int pos = atomicAdd(&cnt[d], 1);
    if (pos < CAP) bucket[d * CAP + pos] = src[e];
    return;
  }
  if (blk < 2852) {  // weight transposes: 90112 elements
    int i = (blk - 2500) * 256 + threadIdx.x;
    if (i < 8192) {  // W1a: 64x128 -> T1a[128][64]
      int c = i >> 6, k = i & 63;
      T1a[i] = f2b(W1a[k * 128 + c]);
    } else if (i < 24576) {
      int l = i - 8192, c = l >> 7, k = l & 127;
      T1b[l] = f2b(W1b[k * 128 + c]);
    } else if (i < 40960) {
      int l = i - 24576, c = l >> 7, k = l & 127;
      T2a[l] = f2b(W2a[k * 128 + c]);
    } else if (i < 57344) {
      int l = i - 40960, c = l >> 7, k = l & 127;
      T2b[l] = f2b(W2b[k * 128 + c]);
    } else if (i < 73728) {
      int l = i - 57344, c = l >> 7, k = l & 127;
      T3a[l] = f2b(W3a[k * 128 + c]);
    } else if (i < 90112) {
      int l = i - 73728, c = l >> 7, k = l & 127;
      T3b[l] = f2b(W3b[k * 128 + c]);
    }
    return;
  }
  if (blk < 4102) {  // x conversion: 2,560,000 f32 = 1250 blocks x 256 x 8
    const int base = ((blk - 2852) * 256 + threadIdx.x) * 8;
    const float4 v0 = *(const float4*)(x + base);
    const float4 v1 = *(const float4*)(x + base + 4);
    uint4 o;
    o.x = pack2(v0.x, v0.y);
    o.y = pack2(v0.z, v0.w);
    o.z = pack2(v1.x, v1.y);
    o.w = pack2(v1.z, v1.w);
    *(uint4*)(xb + base) = o;
    return;
  }
  // zero g: 128 blocks x 256 = 32768 floats exact
  g[(blk - 4102) * 256 + threadIdx.x] = 0.0f;
}

// ---------------------------------------------------------------------------
// Fused GIN layer, 512 thr (8 waves), BM=32 nodes/block, 1250 blocks.
// Index staging: block's bucket slice (8 KB) -> LDS, coalesced.
// Gather: 2 rows/wave (32 lanes/row, uint2 8B/lane for K=128), two passes
// over the 32-row tile, 8-deep unrolled edge loop; indices from LDS.
// Lean register footprint (~50 live) to fit the 64-VGPR cap at 8 waves/EU
// with zero spill while keeping 8 outstanding gather loads.
// Phase 1: zt^T = Ta @ Z^T (wave = 16 zt-cols). Phase 2: H = relu(zt@Tb+bb)
// (wave = 16 rows x 32 cols). POOL variant pools the H tile straight into g.
// LDS 24KB: Z tile @0 (swizzled), zts @8192 (swizzled), idx @16384 (8KB);
// POOL reuses [0,16KB) as a f32 [32][128] buffer. Swizzle: byte^=((row&7)<<4).
// ---------------------------------------------------------------------------
template <int K1, bool POOL>
__global__ __launch_bounds__(512, 8) void layer_kernel(
    const ushort_t* __restrict__ Hin, const int* __restrict__ bucket,
    const int* __restrict__ cnt, const float* __restrict__ epsP,
    const ushort_t* __restrict__ Ta, const float* __restrict__ ba,
    const ushort_t* __restrict__ Tb, const float* __restrict__ bb,
    ushort_t* __restrict__ Hout, const int* __restrict__ batch,
    float* __restrict__ g) {
  __shared__ __align__(16) char smem[24576];
  char* zts = smem + 8192;
  int* ldsidx = (int*)(smem + 16384);  // [32][64] ints = 8 KB
  const int tid = threadIdx.x;
  const int wid = tid >> 6;  // 0..7
  const int lane = tid & 63;
  const int l15 = lane & 15;
  const int kg = (lane >> 4) * 8;
  const int crow = (lane >> 4) * 4;
  const int row0 = blockIdx.x * 32;
  const float e1 = 1.0f + *epsP;

  // ---- stage this block's bucket slice into LDS (coalesced, 1 uint4/thr) ----
  ((uint4*)ldsidx)[tid] = ((const uint4*)(bucket + row0 * CAP))[tid];
  __syncthreads();

  // ---- gather phase: 2 rows per wave (32 lanes/row), 2 passes -> 32 rows ----
  {
    const int l = lane & 31;
    const int half = lane >> 5;  // 0 or 1
#pragma unroll 1
    for (int pass = 0; pass < 2; pass++) {
      const int r = pass * 16 + wid * 2 + half;  // 0..31
      const int node = row0 + r;
      int n = cnt[node];
      if (n > CAP) n = CAP;
      const int* __restrict__ bl = ldsidx + r * CAP;
      if (K1 == 128) {
        const uint2* __restrict__ h4 = (const uint2*)Hin;  // 32 uint2 per row
        float a0 = 0.f, a1 = 0.f, a2 = 0.f, a3 = 0.f;
        int j = 0;
        for (; j + 8 <= n; j += 8) {
          const uint4 i0 = *(const uint4*)(bl + j);
          const uint4 i1 = *(const uint4*)(bl + j + 4);
          const uint_t pe[8] = {i0.x, i0.y, i0.z, i0.w,
                                i1.x, i1.y, i1.z, i1.w};
          uint2 v[8];
#pragma unroll
          for (int q = 0; q < 8; q++) v[q] = h4[(size_t)pe[q] * 32 + l];
#pragma unroll
          for (int q = 0; q < 8; q++) {
            a0 += b2f_lo(v[q].x);
            a1 += b2f_hi(v[q].x);
            a2 += b2f_lo(v[q].y);
            a3 += b2f_hi(v[q].y);
          }
        }
        if (j + 4 <= n) {
          const uint4 i0 = *(const uint4*)(bl + j);
          const uint_t pe[4] = {i0.x, i0.y, i0.z, i0.w};
          uint2 v[4];
#pragma unroll
          for (int q = 0; q < 4; q++) v[q] = h4[(size_t)pe[q] * 32 + l];
#pragma unroll
          for (int q = 0; q < 4; q++) {
            a0 += b2f_lo(v[q].x);
            a1 += b2f_hi(v[q].x);
            a2 += b2f_lo(v[q].y);
            a3 += b2f_hi(v[q].y);
          }
          j += 4;
        }
        for (; j < n; j++) {
          uint2 v = h4[(size_t)bl[j] * 32 + l];
          a0 += b2f_lo(v.x);
          a1 += b2f_hi(v.x);
          a2 += b2f_lo(v.y);
          a3 += b2f_hi(v.y);
        }
        const uint2 hv = h4[(size_t)node * 32 + l];
        uint2 o;
        o.x = pack2(fmaf(e1, b2f_lo(hv.x), a0), fmaf(e1, b2f_hi(hv.x), a1));
        o.y = pack2(fmaf(e1, b2f_lo(hv.y), a2), fmaf(e1, b2f_hi(hv.y), a3));
        *(uint2*)(smem + ((r * 256 + l * 8) ^ ((r & 7) << 4))) = o;
      } else {  // K1 == 64: row = 128 B = 32 uints, 1 uint/lane
        const uint_t* __restrict__ h2 = (const uint_t*)Hin;
        float a0 = 0.f, a1 = 0.f;
        int j = 0;
        for (; j + 8 <= n; j += 8) {
          const uint4 i0 = *(const uint4*)(bl + j);
          const uint4 i1 = *(const uint4*)(bl + j + 4);
          const uint_t pe[8] = {i0.x, i0.y, i0.z, i0.w,
                                i1.x, i1.y, i1.z, i1.w};
          uint_t v[8];
#pragma unroll
          for (int q = 0; q < 8; q++) v[q] = h2[(size_t)pe[q] * 32 + l];
#pragma unroll
          for (int q = 0; q < 8; q++) {
            a0 += b2f_lo(v[q]);
            a1 += b2f_hi(v[q]);
          }
        }
        if (j + 4 <= n) {
          const uint4 i0 = *(const uint4*)(bl + j);
          const uint_t pe[4] = {i0.x, i0.y, i0.z, i0.w};
          uint_t v[4];
#pragma unroll
          for (int q = 0; q < 4; q++) v[q] = h2[(size_t)pe[q] * 32 + l];
#pragma unroll
          for (int q = 0; q < 4; q++) {
            a0 += b2f_lo(v[q]);
            a1 += b2f_hi(v[q]);
          }
          j += 4;
        }
        for (; j < n; j++) {
          uint_t v = h2[(size_t)bl[j] * 32 + l];
          a0 += b2f_lo(v);
          a1 += b2f_hi(v);
        }
        const uint_t hv = h2[(size_t)node * 32 + l];
        uint_t o = pack2(fmaf(e1, b2f_lo(hv), a0), fmaf(e1, b2f_hi(hv), a1));
        *(uint_t*)(smem + ((r * 128 + l * 4) ^ ((r & 7) << 4))) = o;
      }
    }
  }
  __syncthreads();

  // ---- phase 1: zt^T = Ta @ Z^T; wave wid owns zt cols wid*16..+16 ----
  {
    f32x4 acc[2] = {};
#pragma unroll
    for (int kt = 0; kt < K1; kt += 32) {
      bf16x8 a = *(const bf16x8*)(Ta + (size_t)(wid * 16 + l15) * K1 + kt + kg);
      bf16x8 b[2];
#pragma unroll
      for (int nf = 0; nf < 2; nf++) {
        const int R = nf * 16 + l15;
        b[nf] = *(const bf16x8*)(
            smem + ((R * (K1 * 2) + (kt + kg) * 2) ^ ((R & 7) << 4)));
      }
#pragma unroll
      for (int nf = 0; nf < 2; nf++)
        acc[nf] =
            __builtin_amdgcn_mfma_f32_16x16x32_bf16(a, b[nf], acc[nf], 0, 0, 0);
    }
    // lane holds zt[m][c..c+3]: m = nf*16+l15, c = wid*16+crow
    const int c = wid * 16 + crow;
    const float4 bv = *(const float4*)(ba + c);
#pragma unroll
    for (int nf = 0; nf < 2; nf++) {
      const int m = nf * 16 + l15;
      const f32x4 v = acc[nf];
      uint_t u0 = pack2(fmaxf(v[0] + bv.x, 0.f), fmaxf(v[1] + bv.y, 0.f));
      uint_t u1 = pack2(fmaxf(v[2] + bv.z, 0.f), fmaxf(v[3] + bv.w, 0.f));
      *(uint2*)(zts + ((m * 256 + c * 2) ^ ((m & 7) << 4))) =
          make_uint2(u0, u1);
    }
  }
  __syncthreads();

  // ---- phase 2: H = relu(zt @ Tb + bb); wave = 16 rows x 32 cols ----
  {
    const int wm = wid & 1;
    const int wn = wid >> 1;  // 0..3
    const int col0 = wn * 32;
    f32x4 acc[2] = {};
#pragma unroll
    for (int kt = 0; kt < 128; kt += 32) {
      const int R = wm * 16 + l15;
      bf16x8 a =
          *(const bf16x8*)(zts + ((R * 256 + (kt + kg) * 2) ^ ((R & 7) << 4)));
      bf16x8 b[2];
#pragma unroll
      for (int nf = 0; nf < 2; nf++)
        b[nf] = *(const bf16x8*)(Tb + (size_t)(col0 + nf * 16 + l15) * 128 +
                                 kt + kg);
#pragma unroll
      for (int nf = 0; nf < 2; nf++)
        acc[nf] =
            __builtin_amdgcn_mfma_f32_16x16x32_bf16(a, b[nf], acc[nf], 0, 0, 0);
    }
    if (!POOL) {
#pragma unroll
      for (int nf = 0; nf < 2; nf++) {
        const int cc = col0 + nf * 16 + l15;
        const float bv = bb[cc];
        const f32x4 v = acc[nf];
#pragma unroll
        for (int r = 0; r < 4; r++) {
          float o = fmaxf(v[r] + bv, 0.0f);
          Hout[(size_t)(row0 + wm * 16 + crow + r) * 128 + cc] = f2b(o);
        }
      }
    } else {
      // stage relu(H) tile as f32 into [0,16KB) (Z+zts regions, post-sync)
      __syncthreads();  // all zts reads done before overwrite
#pragma unroll
      for (int nf = 0; nf < 2; nf++) {
        const int cc = col0 + nf * 16 + l15;
        const float bv = bb[cc];
        const f32x4 v = acc[nf];
#pragma unroll
        for (int r = 0; r < 4; r++) {
          const int R = wm * 16 + crow + r;
          *(float*)(smem + ((R * 512 + cc * 4) ^ ((R & 7) << 4))) =
              fmaxf(v[r] + bv, 0.0f);
        }
      }
      __syncthreads();
      if (tid < 128) {  // thread t owns feature t; batch sorted
        float acc2 = 0.f;
        int cur = batch[row0];
#pragma unroll 4
        for (int r = 0; r < 32; r++) {
          const int bn = batch[row0 + r];
          if (bn != cur) {
            atomicAdd(&g[(size_t)cur * HIDDEN + tid], acc2);
            acc2 = 0.f;
            cur = bn;
          }
          acc2 +=
              *(const float*)(smem + ((r * 512 + tid * 4) ^ ((r & 7) << 4)));
        }
        atomicAdd(&g[(size_t)cur * HIDDEN + tid], acc2);
      }
    }
  }
}

// ---------------------------------------------------------------------------
// Head (f32): out[row] = relu(g[row] @ W1 + b1) @ W2 + b2.
// ---------------------------------------------------------------------------
__global__ __launch_bounds__(128) void head_kernel(
    const float* __restrict__ g, const float* __restrict__ W1,
    const float* __restrict__ b1, const float* __restrict__ W2,
    const float* __restrict__ b2, float* __restrict__ out) {
  const int row = blockIdx.x;
  const int t = threadIdx.x;
  __shared__ float grow[HIDDEN];
  __shared__ float part[2];
  grow[t] = g[(size_t)row * HIDDEN + t];
  __syncthreads();
  float acc = b1[t];
#pragma unroll 8
  for (int k = 0; k < HIDDEN; k++) acc = fmaf(grow[k], W1[k * HIDDEN + t], acc);
  acc = fmaxf(acc, 0.0f);
  float v = acc * W2[t];
#pragma unroll
  for (int off = 32; off > 0; off >>= 1) v += __shfl_down(v, off);
  if ((t & 63) == 0) part[t >> 6] = v;
  __syncthreads();
  if (t == 0) out[row] = part[0] + part[1] + b2[0];
}

// ---------------------------------------------------------------------------
extern "C" void kernel_launch(void* const* d_in, const int* in_sizes, int n_in,
                              void* d_out, int out_size, void* d_ws,
                              size_t ws_size, hipStream_t stream) {
  const float* x = (const float*)d_in[0];
  const int* ei = (const int*)d_in[1];
  const int* src = ei;
  const int* dst = ei + N_EDGES;
  const int* batch = (const int*)d_in[3];
  const float* eps1 = (const float*)d_in[4];
  const float* W1a = (const float*)d_in[5];
  const float* b1a = (const float*)d_in[6];
  const float* W1b = (const float*)d_in[7];
  const float* b1b = (const float*)d_in[8];
  const float* eps2 = (const float*)d_in[9];
  const float* W2a = (const float*)d_in[10];
  const float* b2a = (const float*)d_in[11];
  const float* W2b = (const float*)d_in[12];
  const float* b2b = (const float*)d_in[13];
  const float* eps3 = (const float*)d_in[14];
  const float* W3a = (const float*)d_in[15];
  const float* b3a = (const float*)d_in[16];
  const float* W3b = (const float*)d_in[17];
  const float* b3b = (const float*)d_in[18];
  const float* l1W = (const float*)d_in[19];
  const float* l1b = (const float*)d_in[20];
  const float* l2W = (const float*)d_in[21];
  const float* l2b = (const float*)d_in[22];
  float* out = (float*)d_out;

  char* ws = (char*)d_ws;
  int* cnt = (int*)(ws + 0);                   // 160 KB (pad 256K)
  int* bucket = (int*)(ws + 262144);           // 10.24 MB
  ushort_t* xb = (ushort_t*)(ws + 10502144);   // 5.12 MB
  ushort_t* hA = (ushort_t*)(ws + 15622144);   // 10.24 MB
  ushort_t* hB = (ushort_t*)(ws + 25862144);   // 10.24 MB
  ushort_t* T1a = (ushort_t*)(ws + 36102144);  // 16 KB
  ushort_t* T1b = (ushort_t*)(ws + 36118528);  // 32 KB
  ushort_t* T2a = (ushort_t*)(ws + 36151296);  // 32 KB
  ushort_t* T2b = (ushort_t*)(ws + 36184064);  // 32 KB
  ushort_t* T3a = (ushort_t*)(ws + 36216832);  // 32 KB
  ushort_t* T3b = (ushort_t*)(ws + 36249600);  // 32 KB
  float* g = (float*)(ws + 36282368);          // 128 KB

  const int LGRID = N_NODES / 32;  // 1250

  hipMemsetAsync(cnt, 0, (size_t)N_NODES * sizeof(int), stream);
  prep_kernel<<<4230, 256, 0, stream>>>(src, dst, cnt, bucket, W1a, W1b, W2a,
                                        W2b, W3a, W3b, x, T1a, T1b, T2a, T2b,
                                        T3a, T3b, xb, g);
  layer_kernel<64, false><<<LGRID, 512, 0, stream>>>(
      xb, bucket, cnt, eps1, T1a, b1a, T1b, b1b, hA, nullptr, nullptr);
  layer_kernel<128, false><<<LGRID, 512, 0, stream>>>(
      hA, bucket, cnt, eps2, T2a, b2a, T2b, b2b, hB, nullptr, nullptr);
  layer_kernel<128, true><<<LGRID, 512, 0, stream>>>(
      hB, bucket, cnt, eps3, T3a, b3a, T3b, b3b, nullptr, batch, g);
  head_kernel<<<N_GRAPHS, 128, 0, stream>>>(g, l1W, l1b, l2W, l2b, out);
}

// Round 2
// 143.570 us; speedup vs baseline: 1.0614x; 1.0614x over previous
//
#include <hip/hip_runtime.h>
#include <hip/hip_bf16.h>

#define N_NODES 40000
#define N_EDGES 640000
#define N_FEAT 64
#define HIDDEN 128
#define N_GRAPHS 256
#define CAP 64  // max in-degree (deg ~ Poisson(16); P(>64) ~ 1e-19)

typedef unsigned short ushort_t;
typedef unsigned int uint_t;
typedef __bf16 bf16x8 __attribute__((ext_vector_type(8)));
typedef float f32x4 __attribute__((ext_vector_type(4)));

__device__ inline float b2f_lo(uint_t v) {
  return __builtin_bit_cast(float, v << 16);
}
__device__ inline float b2f_hi(uint_t v) {
  return __builtin_bit_cast(float, v & 0xffff0000u);
}
__device__ inline ushort_t f2b(float f) {
  return __builtin_bit_cast(ushort_t, __float2bfloat16(f));
}
__device__ inline uint_t pack2(float lo, float hi) {
  return (uint_t)f2b(lo) | ((uint_t)f2b(hi) << 16);
}

// ---------------------------------------------------------------------------
// zero_cnt: parallel memset of cnt[40000]. Replaces hipMemsetAsync, whose
// small-fill path (fillBufferAligned, tiny grid, latency-bound loop) was
// measured at ~43.5 us per iteration in rocprof. 157 blocks x 256 thr ~ 2 us.
// ---------------------------------------------------------------------------
__global__ __launch_bounds__(256) void zero_cnt_kernel(int* __restrict__ cnt) {
  const int i = blockIdx.x * 256 + threadIdx.x;
  if (i < N_NODES) cnt[i] = 0;
}

// ---------------------------------------------------------------------------
// Prep: blocks [0,2500): bucket fill (int atomic bump).
//       blocks [2500,2852): weight transposes f32[K][128] -> bf16 [128][K].
//       blocks [2852,4102): x f32 -> bf16, VECTORIZED 8 floats/thread.
//       blocks [4102,4230): zero g.
// ---------------------------------------------------------------------------
__global__ __launch_bounds__(256) void prep_kernel(
    const int* __restrict__ src, const int* __restrict__ dst,
    int* __restrict__ cnt, int* __restrict__ bucket,
    const float* __restrict__ W1a, const float* __restrict__ W1b,
    const float* __restrict__ W2a, const float* __restrict__ W2b,
    const float* __restrict__ W3a, const float* __restrict__ W3b,
    const float* __restrict__ x, ushort_t* __restrict__ T1a,
    ushort_t* __restrict__ T1b, ushort_t* __restrict__ T2a,
    ushort_t* __restrict__ T2b, ushort_t* __restrict__ T3a,
    ushort_t* __restrict__ T3b, ushort_t* __restrict__ xb,
    float* __restrict__ g) {
  const int blk = blockIdx.x;
  if (blk < 2500) {
    int e = blk * 256 + threadIdx.x;  // exactly N_EDGES
    int d = dst[e];
    int pos = atomicAdd(&cnt[d], 1);
    if (pos < CAP) bucket[d * CAP + pos] = src[e];
    return;
  }
  if (blk < 2852) {  // weight transposes: 90112 elements
    int i = (blk - 2500) * 256 + threadIdx.x;
    if (i < 8192) {  // W1a: 64x128 -> T1a[128][64]
      int c = i >> 6, k = i & 63;
      T1a[i] = f2b(W1a[k * 128 + c]);
    } else if (i < 24576) {
      int l = i - 8192, c = l >> 7, k = l & 127;
      T1b[l] = f2b(W1b[k * 128 + c]);
    } else if (i < 40960) {
      int l = i - 24576, c = l >> 7, k = l & 127;
      T2a[l] = f2b(W2a[k * 128 + c]);
    } else if (i < 57344) {
      int l = i - 40960, c = l >> 7, k = l & 127;
      T2b[l] = f2b(W2b[k * 128 + c]);
    } else if (i < 73728) {
      int l = i - 57344, c = l >> 7, k = l & 127;
      T3a[l] = f2b(W3a[k * 128 + c]);
    } else if (i < 90112) {
      int l = i - 73728, c = l >> 7, k = l & 127;
      T3b[l] = f2b(W3b[k * 128 + c]);
    }
    return;
  }
  if (blk < 4102) {  // x conversion: 2,560,000 f32 = 1250 blocks x 256 x 8
    const int base = ((blk - 2852) * 256 + threadIdx.x) * 8;
    const float4 v0 = *(const float4*)(x + base);
    const float4 v1 = *(const float4*)(x + base + 4);
    uint4 o;
    o.x = pack2(v0.x, v0.y);
    o.y = pack2(v0.z, v0.w);
    o.z = pack2(v1.x, v1.y);
    o.w = pack2(v1.z, v1.w);
    *(uint4*)(xb + base) = o;
    return;
  }
  // zero g: 128 blocks x 256 = 32768 floats exact
  g[(blk - 4102) * 256 + threadIdx.x] = 0.0f;
}

// ---------------------------------------------------------------------------
// Fused GIN layer, 512 thr (8 waves), BM=32 nodes/block, 1250 blocks.
// Index staging: block's bucket slice (8 KB) -> LDS, coalesced.
// Gather: 4 rows/wave CONCURRENT (16 lanes/row, uint4 16B/lane for K=128),
// 8-deep unrolled edge loop; indices from LDS (ds_read).
// Phase 1: zt^T = Ta @ Z^T (wave = 16 zt-cols). Phase 2: H = relu(zt@Tb+bb)
// (wave = 16 rows x 32 cols). POOL variant pools the H tile straight into g.
// LDS 24KB: Z tile @0 (swizzled), zts @8192 (swizzled), idx @16384 (8KB);
// POOL reuses [0,16KB) as a f32 [32][128] buffer. Swizzle: byte^=((row&7)<<4).
// ---------------------------------------------------------------------------
template <int K1, bool POOL>
__global__ __launch_bounds__(512, 8) void layer_kernel(
    const ushort_t* __restrict__ Hin, const int* __restrict__ bucket,
    const int* __restrict__ cnt, const float* __restrict__ epsP,
    const ushort_t* __restrict__ Ta, const float* __restrict__ ba,
    const ushort_t* __restrict__ Tb, const float* __restrict__ bb,
    ushort_t* __restrict__ Hout, const int* __restrict__ batch,
    float* __restrict__ g) {
  __shared__ __align__(16) char smem[24576];
  char* zts = smem + 8192;
  int* ldsidx = (int*)(smem + 16384);  // [32][64] ints = 8 KB
  const int tid = threadIdx.x;
  const int wid = tid >> 6;  // 0..7
  const int lane = tid & 63;
  const int l15 = lane & 15;
  const int kg = (lane >> 4) * 8;
  const int crow = (lane >> 4) * 4;
  const int row0 = blockIdx.x * 32;
  const float e1 = 1.0f + *epsP;

  // ---- stage this block's bucket slice into LDS (coalesced, 1 uint4/thr) ----
  ((uint4*)ldsidx)[tid] = ((const uint4*)(bucket + row0 * CAP))[tid];
  __syncthreads();

  // ---- gather phase: 4 rows per wave, all concurrent (16 lanes/row) ----
  {
    const int r = wid * 4 + (lane >> 4);  // 0..31
    const int l = lane & 15;
    const int node = row0 + r;
    int n = cnt[node];
    if (n > CAP) n = CAP;
    const int* __restrict__ bl = ldsidx + r * CAP;
    if (K1 == 128) {
      const uint4* __restrict__ h8 = (const uint4*)Hin;  // 16 uint4 per row
      float a0 = 0.f, a1 = 0.f, a2 = 0.f, a3 = 0.f;
      float a4 = 0.f, a5 = 0.f, a6 = 0.f, a7 = 0.f;
      int j = 0;
      for (; j + 8 <= n; j += 8) {
        const uint4 i0 = *(const uint4*)(bl + j);
        const uint4 i1 = *(const uint4*)(bl + j + 4);
        const uint_t pe[8] = {i0.x, i0.y, i0.z, i0.w, i1.x, i1.y, i1.z, i1.w};
        uint4 v[8];
#pragma unroll
        for (int q = 0; q < 8; q++) v[q] = h8[(size_t)pe[q] * 16 + l];
#pragma unroll
        for (int q = 0; q < 8; q++) {
          a0 += b2f_lo(v[q].x);
          a1 += b2f_hi(v[q].x);
          a2 += b2f_lo(v[q].y);
          a3 += b2f_hi(v[q].y);
          a4 += b2f_lo(v[q].z);
          a5 += b2f_hi(v[q].z);
          a6 += b2f_lo(v[q].w);
          a7 += b2f_hi(v[q].w);
        }
      }
      if (j + 4 <= n) {
        const uint4 i0 = *(const uint4*)(bl + j);
        const uint_t pe[4] = {i0.x, i0.y, i0.z, i0.w};
        uint4 v[4];
#pragma unroll
        for (int q = 0; q < 4; q++) v[q] = h8[(size_t)pe[q] * 16 + l];
#pragma unroll
        for (int q = 0; q < 4; q++) {
          a0 += b2f_lo(v[q].x);
          a1 += b2f_hi(v[q].x);
          a2 += b2f_lo(v[q].y);
          a3 += b2f_hi(v[q].y);
          a4 += b2f_lo(v[q].z);
          a5 += b2f_hi(v[q].z);
          a6 += b2f_lo(v[q].w);
          a7 += b2f_hi(v[q].w);
        }
        j += 4;
      }
      for (; j < n; j++) {
        uint4 v = h8[(size_t)bl[j] * 16 + l];
        a0 += b2f_lo(v.x);
        a1 += b2f_hi(v.x);
        a2 += b2f_lo(v.y);
        a3 += b2f_hi(v.y);
        a4 += b2f_lo(v.z);
        a5 += b2f_hi(v.z);
        a6 += b2f_lo(v.w);
        a7 += b2f_hi(v.w);
      }
      const uint4 hv = h8[(size_t)node * 16 + l];
      uint4 o;
      o.x = pack2(fmaf(e1, b2f_lo(hv.x), a0), fmaf(e1, b2f_hi(hv.x), a1));
      o.y = pack2(fmaf(e1, b2f_lo(hv.y), a2), fmaf(e1, b2f_hi(hv.y), a3));
      o.z = pack2(fmaf(e1, b2f_lo(hv.z), a4), fmaf(e1, b2f_hi(hv.z), a5));
      o.w = pack2(fmaf(e1, b2f_lo(hv.w), a6), fmaf(e1, b2f_hi(hv.w), a7));
      *(uint4*)(smem + ((r * 256 + l * 16) ^ ((r & 7) << 4))) = o;
    } else {  // K1 == 64: row = 128 B = 16 uint2
      const uint2* __restrict__ h4 = (const uint2*)Hin;
      float a0 = 0.f, a1 = 0.f, a2 = 0.f, a3 = 0.f;
      int j = 0;
      for (; j + 8 <= n; j += 8) {
        const uint4 i0 = *(const uint4*)(bl + j);
        const uint4 i1 = *(const uint4*)(bl + j + 4);
        const uint_t pe[8] = {i0.x, i0.y, i0.z, i0.w, i1.x, i1.y, i1.z, i1.w};
        uint2 v[8];
#pragma unroll
        for (int q = 0; q < 8; q++) v[q] = h4[(size_t)pe[q] * 16 + l];
#pragma unroll
        for (int q = 0; q < 8; q++) {
          a0 += b2f_lo(v[q].x);
          a1 += b2f_hi(v[q].x);
          a2 += b2f_lo(v[q].y);
          a3 += b2f_hi(v[q].y);
        }
      }
      if (j + 4 <= n) {
        const uint4 i0 = *(const uint4*)(bl + j);
        const uint_t pe[4] = {i0.x, i0.y, i0.z, i0.w};
        uint2 v[4];
#pragma unroll
        for (int q = 0; q < 4; q++) v[q] = h4[(size_t)pe[q] * 16 + l];
#pragma unroll
        for (int q = 0; q < 4; q++) {
          a0 += b2f_lo(v[q].x);
          a1 += b2f_hi(v[q].x);
          a2 += b2f_lo(v[q].y);
          a3 += b2f_hi(v[q].y);
        }
        j += 4;
      }
      for (; j < n; j++) {
        uint2 v = h4[(size_t)bl[j] * 16 + l];
        a0 += b2f_lo(v.x);
        a1 += b2f_hi(v.x);
        a2 += b2f_lo(v.y);
        a3 += b2f_hi(v.y);
      }
      const uint2 hv = h4[(size_t)node * 16 + l];
      uint2 o;
      o.x = pack2(fmaf(e1, b2f_lo(hv.x), a0), fmaf(e1, b2f_hi(hv.x), a1));
      o.y = pack2(fmaf(e1, b2f_lo(hv.y), a2), fmaf(e1, b2f_hi(hv.y), a3));
      *(uint2*)(smem + ((r * 128 + l * 8) ^ ((r & 7) << 4))) = o;
    }
  }
  __syncthreads();

  // ---- phase 1: zt^T = Ta @ Z^T; wave wid owns zt cols wid*16..+16 ----
  {
    f32x4 acc[2] = {};
#pragma unroll
    for (int kt = 0; kt < K1; kt += 32) {
      bf16x8 a = *(const bf16x8*)(Ta + (size_t)(wid * 16 + l15) * K1 + kt + kg);
      bf16x8 b[2];
#pragma unroll
      for (int nf = 0; nf < 2; nf++) {
        const int R = nf * 16 + l15;
        b[nf] = *(const bf16x8*)(
            smem + ((R * (K1 * 2) + (kt + kg) * 2) ^ ((R & 7) << 4)));
      }
#pragma unroll
      for (int nf = 0; nf < 2; nf++)
        acc[nf] =
            __builtin_amdgcn_mfma_f32_16x16x32_bf16(a, b[nf], acc[nf], 0, 0, 0);
    }
    // lane holds zt[m][c..c+3]: m = nf*16+l15, c = wid*16+crow
    const int c = wid * 16 + crow;
    const float4 bv = *(const float4*)(ba + c);
#pragma unroll
    for (int nf = 0; nf < 2; nf++) {
      const int m = nf * 16 + l15;
      const f32x4 v = acc[nf];
      uint_t u0 = pack2(fmaxf(v[0] + bv.x, 0.f), fmaxf(v[1] + bv.y, 0.f));
      uint_t u1 = pack2(fmaxf(v[2] + bv.z, 0.f), fmaxf(v[3] + bv.w, 0.f));
      *(uint2*)(zts + ((m * 256 + c * 2) ^ ((m & 7) << 4))) =
          make_uint2(u0, u1);
    }
  }
  __syncthreads();

  // ---- phase 2: H = relu(zt @ Tb + bb); wave = 16 rows x 32 cols ----
  {
    const int wm = wid & 1;
    const int wn = wid >> 1;  // 0..3
    const int col0 = wn * 32;
    f32x4 acc[2] = {};
#pragma unroll
    for (int kt = 0; kt < 128; kt += 32) {
      const int R = wm * 16 + l15;
      bf16x8 a =
          *(const bf16x8*)(zts + ((R * 256 + (kt + kg) * 2) ^ ((R & 7) << 4)));
      bf16x8 b[2];
#pragma unroll
      for (int nf = 0; nf < 2; nf++)
        b[nf] = *(const bf16x8*)(Tb + (size_t)(col0 + nf * 16 + l15) * 128 +
                                 kt + kg);
#pragma unroll
      for (int nf = 0; nf < 2; nf++)
        acc[nf] =
            __builtin_amdgcn_mfma_f32_16x16x32_bf16(a, b[nf], acc[nf], 0, 0, 0);
    }
    if (!POOL) {
#pragma unroll
      for (int nf = 0; nf < 2; nf++) {
        const int cc = col0 + nf * 16 + l15;
        const float bv = bb[cc];
        const f32x4 v = acc[nf];
#pragma unroll
        for (int r = 0; r < 4; r++) {
          float o = fmaxf(v[r] + bv, 0.0f);
          Hout[(size_t)(row0 + wm * 16 + crow + r) * 128 + cc] = f2b(o);
        }
      }
    } else {
      // stage relu(H) tile as f32 into [0,16KB) (Z+zts regions, post-sync)
      __syncthreads();  // all zts reads done before overwrite
#pragma unroll
      for (int nf = 0; nf < 2; nf++) {
        const int cc = col0 + nf * 16 + l15;
        const float bv = bb[cc];
        const f32x4 v = acc[nf];
#pragma unroll
        for (int r = 0; r < 4; r++) {
          const int R = wm * 16 + crow + r;
          *(float*)(smem + ((R * 512 + cc * 4) ^ ((R & 7) << 4))) =
              fmaxf(v[r] + bv, 0.0f);
        }
      }
      __syncthreads();
      if (tid < 128) {  // thread t owns feature t; batch sorted
        float acc2 = 0.f;
        int cur = batch[row0];
#pragma unroll 4
        for (int r = 0; r < 32; r++) {
          const int bn = batch[row0 + r];
          if (bn != cur) {
            atomicAdd(&g[(size_t)cur * HIDDEN + tid], acc2);
            acc2 = 0.f;
            cur = bn;
          }
          acc2 +=
              *(const float*)(smem + ((r * 512 + tid * 4) ^ ((r & 7) << 4)));
        }
        atomicAdd(&g[(size_t)cur * HIDDEN + tid], acc2);
      }
    }
  }
}

// ---------------------------------------------------------------------------
// Head (f32): out[row] = relu(g[row] @ W1 + b1) @ W2 + b2.
// ---------------------------------------------------------------------------
__global__ __launch_bounds__(128) void head_kernel(
    const float* __restrict__ g, const float* __restrict__ W1,
    const float* __restrict__ b1, const float* __restrict__ W2,
    const float* __restrict__ b2, float* __restrict__ out) {
  const int row = blockIdx.x;
  const int t = threadIdx.x;
  __shared__ float grow[HIDDEN];
  __shared__ float part[2];
  grow[t] = g[(size_t)row * HIDDEN + t];
  __syncthreads();
  float acc = b1[t];
#pragma unroll 8
  for (int k = 0; k < HIDDEN; k++) acc = fmaf(grow[k], W1[k * HIDDEN + t], acc);
  acc = fmaxf(acc, 0.0f);
  float v = acc * W2[t];
#pragma unroll
  for (int off = 32; off > 0; off >>= 1) v += __shfl_down(v, off);
  if ((t & 63) == 0) part[t >> 6] = v;
  __syncthreads();
  if (t == 0) out[row] = part[0] + part[1] + b2[0];
}

// ---------------------------------------------------------------------------
extern "C" void kernel_launch(void* const* d_in, const int* in_sizes, int n_in,
                              void* d_out, int out_size, void* d_ws,
                              size_t ws_size, hipStream_t stream) {
  const float* x = (const float*)d_in[0];
  const int* ei = (const int*)d_in[1];
  const int* src = ei;
  const int* dst = ei + N_EDGES;
  const int* batch = (const int*)d_in[3];
  const float* eps1 = (const float*)d_in[4];
  const float* W1a = (const float*)d_in[5];
  const float* b1a = (const float*)d_in[6];
  const float* W1b = (const float*)d_in[7];
  const float* b1b = (const float*)d_in[8];
  const float* eps2 = (const float*)d_in[9];
  const float* W2a = (const float*)d_in[10];
  const float* b2a = (const float*)d_in[11];
  const float* W2b = (const float*)d_in[12];
  const float* b2b = (const float*)d_in[13];
  const float* eps3 = (const float*)d_in[14];
  const float* W3a = (const float*)d_in[15];
  const float* b3a = (const float*)d_in[16];
  const float* W3b = (const float*)d_in[17];
  const float* b3b = (const float*)d_in[18];
  const float* l1W = (const float*)d_in[19];
  const float* l1b = (const float*)d_in[20];
  const float* l2W = (const float*)d_in[21];
  const float* l2b = (const float*)d_in[22];
  float* out = (float*)d_out;

  char* ws = (char*)d_ws;
  int* cnt = (int*)(ws + 0);                   // 160 KB (pad 256K)
  int* bucket = (int*)(ws + 262144);           // 10.24 MB
  ushort_t* xb = (ushort_t*)(ws + 10502144);   // 5.12 MB
  ushort_t* hA = (ushort_t*)(ws + 15622144);   // 10.24 MB
  ushort_t* hB = (ushort_t*)(ws + 25862144);   // 10.24 MB
  ushort_t* T1a = (ushort_t*)(ws + 36102144);  // 16 KB
  ushort_t* T1b = (ushort_t*)(ws + 36118528);  // 32 KB
  ushort_t* T2a = (ushort_t*)(ws + 36151296);  // 32 KB
  ushort_t* T2b = (ushort_t*)(ws + 36184064);  // 32 KB
  ushort_t* T3a = (ushort_t*)(ws + 36216832);  // 32 KB
  ushort_t* T3b = (ushort_t*)(ws + 36249600);  // 32 KB
  float* g = (float*)(ws + 36282368);          // 128 KB

  const int LGRID = N_NODES / 32;  // 1250

  zero_cnt_kernel<<<157, 256, 0, stream>>>(cnt);
  prep_kernel<<<4230, 256, 0, stream>>>(src, dst, cnt, bucket, W1a, W1b, W2a,
                                        W2b, W3a, W3b, x, T1a, T1b, T2a, T2b,
                                        T3a, T3b, xb, g);
  layer_kernel<64, false><<<LGRID, 512, 0, stream>>>(
      xb, bucket, cnt, eps1, T1a, b1a, T1b, b1b, hA, nullptr, nullptr);
  layer_kernel<128, false><<<LGRID, 512, 0, stream>>>(
      hA, bucket, cnt, eps2, T2a, b2a, T2b, b2b, hB, nullptr, nullptr);
  layer_kernel<128, true><<<LGRID, 512, 0, stream>>>(
      hB, bucket, cnt, eps3, T3a, b3a, T3b, b3b, nullptr, batch, g);
  head_kernel<<<N_GRAPHS, 128, 0, stream>>>(g, l1W, l1b, l2W, l2b, out);
}